// Round 6
// baseline (290.721 us; speedup 1.0000x reference)
//
#include <hip/hip_runtime.h>
#include <stdint.h>

#define Mdim 8192
#define Ndim 4096
#define Kdim 4096

#define BM 256
#define BN 256
#define BK 32
#define NT (Kdim / BK)   // 128 K-tiles

typedef float f32x4 __attribute__((ext_vector_type(4)));
typedef __bf16 bf16x8 __attribute__((ext_vector_type(8)));
typedef unsigned short ushort_t;

#define FMAXC 3.3858093490333422e+38f  // FLT_MAX * (1 - 0.005)

__device__ __forceinline__ ushort_t f2bf(float f) {
    unsigned u = __float_as_uint(f);
    u += 0x7fffu + ((u >> 16) & 1u);   // round-to-nearest-even
    return (ushort_t)(u >> 16);
}

__device__ __forceinline__ void gload_lds16(const void* g, void* l) {
    __builtin_amdgcn_global_load_lds(
        (const __attribute__((address_space(1))) uint32_t*)g,
        (__attribute__((address_space(3))) uint32_t*)(uint32_t)(uintptr_t)l,
        16, 0, 0);
}

// ---------------------------------------------------------------------------
// Kernel 1: dequant + CSR outliers -> bf16 weight row. Unchanged (passed).
// ---------------------------------------------------------------------------
__global__ __launch_bounds__(128) void dequant_kernel(
        const int* __restrict__ qw, const float* __restrict__ lut,
        const int* __restrict__ rows, const int* __restrict__ cols,
        const float* __restrict__ vals, ushort_t* __restrict__ w16) {
    __shared__ float wrow[128 * 33];
    __shared__ float slut[16];
    const int o = blockIdx.x;
    const int t = threadIdx.x;

    if (t < 16) slut[t] = lut[o * 16 + t];
    __syncthreads();

    const int q0 = qw[0 * Ndim * 128 + o * 128 + t];
    const int q1 = qw[1 * Ndim * 128 + o * 128 + t];
    const int q2 = qw[2 * Ndim * 128 + o * 128 + t];
    const int q3 = qw[3 * Ndim * 128 + o * 128 + t];
    float* dst = &wrow[t * 33];
#pragma unroll
    for (int j = 0; j < 32; ++j) {
        int idx = (((q0 >> j) & 1) << 3) | (((q1 >> j) & 1) << 2) |
                  (((q2 >> j) & 1) << 1) | ((q3 >> j) & 1);
        dst[j] = slut[idx];
    }
    __syncthreads();

    const int beg = rows[o], end = rows[o + 1];
    for (int k = beg + t; k < end; k += 128) {
        int c = cols[k];
        atomicAdd(&wrow[c + (c >> 5)], vals[k]);
    }
    __syncthreads();

    __align__(16) ushort_t tmp[32];
#pragma unroll
    for (int j = 0; j < 32; ++j) tmp[j] = f2bf(dst[j]);
    uint4* dstg = (uint4*)(w16 + (size_t)o * Kdim + t * 32);
    const uint4* srcg = (const uint4*)tmp;
#pragma unroll
    for (int j = 0; j < 4; ++j) dstg[j] = srcg[j];
}

// ---------------------------------------------------------------------------
// Kernel 2: x f32 -> bf16. Unchanged (HBM-bound, ~30 us).
// ---------------------------------------------------------------------------
__global__ __launch_bounds__(256) void convx_kernel(
        const float* __restrict__ x, ushort_t* __restrict__ y) {
    size_t i = ((size_t)blockIdx.x * 256 + threadIdx.x) * 8;
    float4 a = *(const float4*)(x + i);
    float4 b = *(const float4*)(x + i + 4);
    __align__(16) ushort_t r[8] = {f2bf(a.x), f2bf(a.y), f2bf(a.z), f2bf(a.w),
                                   f2bf(b.x), f2bf(b.y), f2bf(b.z), f2bf(b.w)};
    *(uint4*)(y + i) = *(const uint4*)r;
}

// ---------------------------------------------------------------------------
// Kernel 3: bf16 GEMM, 256x256 tile, BK=32, 4-buffer LDS ring, cross-tile
// register fragment prefetch + T19 sched_group_barrier MFMA:DS_READ
// interleave (per tile: 4 stage-VMEM, then 12x{1 MFMA,1 ds_read}, then
// 20 MFMA) so ds_read issue fills MFMA issue-stall cycles instead of
// backpressuring the wave before the MFMA cluster.
// Pipeline/correctness identical to round 5 (stage distance 3, vmcnt(4)
// per tile, single barrier; RAW/WAR argument in round-5 comments holds).
// ---------------------------------------------------------------------------
__global__ __launch_bounds__(512, 2) void gemm_kernel(
        const ushort_t* __restrict__ A, const ushort_t* __restrict__ Bw,
        const float* __restrict__ bias, float* __restrict__ C) {
    __shared__ __align__(16) char lds[131072];

    // XCD swizzle, bn-fastest: 32 concurrent blocks per XCD share one A panel
    // (L2-resident), stream B via L3. nwg=512 (%8==0).
    const int wgid = blockIdx.x;
    const int swz = (wgid & 7) * 64 + (wgid >> 3);
    const int bn = swz & 15, bm = swz >> 4;
    const int m0 = bm * BM, n0 = bn * BN;

    const int tid = threadIdx.x;
    const int lane = tid & 63, wid = tid >> 6;
    const int wr = wid >> 2, wc = wid & 3;       // 2M x 4N wave grid
    const int fr = lane & 15, kg = lane >> 4;

    // ---- staging geometry (inverse-swizzled global source, linear LDS dest)
    const int sline = tid >> 3;
    const int slot = (tid & 7) ^ (sline & 7);
    const int srow0 = (sline << 1) + (slot >> 2);          // + j*128
    const int skel = (slot & 3) * 8;                       // k elements
    const ushort_t* gA = A + (size_t)(m0 + srow0) * Kdim + skel;
    const ushort_t* gB = Bw + (size_t)(n0 + srow0) * Kdim + skel;

    // ---- ds_read lane offset (row = base + fr, kslot = kg)
    const int offL = (fr >> 1) * 128 + (((((fr & 1) << 2) | kg) ^ (fr >> 1)) << 4);

    f32x4 acc[8][4];
#pragma unroll
    for (int i = 0; i < 8; ++i)
#pragma unroll
        for (int j = 0; j < 4; ++j) acc[i][j] = (f32x4){0.f, 0.f, 0.f, 0.f};

    // running stage pointers: advance BK per tile staged
    const ushort_t* pA = gA;
    const ushort_t* pB = gB;

    auto stageA = [&](int bufd) {
        char* d = lds + bufd * 16384 + tid * 16;
        gload_lds16(pA, d);
        gload_lds16(pA + (size_t)128 * Kdim, d + 8192);
    };
    auto stageB = [&](int bufd) {
        char* d = lds + 65536 + bufd * 16384 + tid * 16;
        gload_lds16(pB, d);
        gload_lds16(pB + (size_t)128 * Kdim, d + 8192);
    };
    auto readFrags = [&](bf16x8 (&FA)[8], bf16x8 (&FB)[4], int bufidx) {
        const char* Ab = lds + bufidx * 16384;
        const char* Bb = lds + 65536 + bufidx * 16384;
#pragma unroll
        for (int n = 0; n < 4; ++n) {
            FA[n] = *(const bf16x8*)(Ab + wr * 8192 + n * 1024 + offL);
            FB[n] = *(const bf16x8*)(Bb + wc * 4096 + n * 1024 + offL);
        }
#pragma unroll
        for (int m = 4; m < 8; ++m)
            FA[m] = *(const bf16x8*)(Ab + wr * 8192 + m * 1024 + offL);
    };
    auto mfmaTile = [&](bf16x8 (&FA)[8], bf16x8 (&FB)[4]) {
        __builtin_amdgcn_s_setprio(1);
#pragma unroll
        for (int m = 0; m < 8; ++m)
#pragma unroll
            for (int n = 0; n < 4; ++n)
                acc[m][n] = __builtin_amdgcn_mfma_f32_16x16x32_bf16(
                    FA[m], FB[n], acc[m][n], 0, 0, 0);
        __builtin_amdgcn_s_setprio(0);
    };
    // T19: force emission = 4 VMEM (stage), then 12x{1 MFMA, 1 DS_READ},
    // then 20 MFMA. Masks: MFMA=0x8, VMEM=0x10, DS_READ=0x100.
    auto schedInterleave = [&]() {
        __builtin_amdgcn_sched_group_barrier(0x010, 4, 0);
#pragma unroll
        for (int i = 0; i < 12; ++i) {
            __builtin_amdgcn_sched_group_barrier(0x008, 1, 0);
            __builtin_amdgcn_sched_group_barrier(0x100, 1, 0);
        }
        __builtin_amdgcn_sched_group_barrier(0x008, 20, 0);
    };

    // ---- prologue: stage tiles 0,1,2 -> bufs 0,1,2
    stageA(0); stageB(0); pA += BK; pB += BK;
    stageA(1); stageB(1); pA += BK; pB += BK;
    stageA(2); stageB(2); pA += BK; pB += BK;
    asm volatile("s_waitcnt vmcnt(4)" ::: "memory");   // tiles 0,1 resident
    asm volatile("s_barrier" ::: "memory");

    bf16x8 FAa[8], FAb[8];
    bf16x8 FBa[4], FBb[4];
    readFrags(FAa, FBa, 0);                            // tile 0 -> set a

#pragma unroll 1
    for (int t = 0; t < NT; t += 2) {
        // ===== half 1: compute tile t (set a); read tile t+1 -> set b =====
        readFrags(FAb, FBb, (t + 1) & 3);              // t+1 <= NT-1 always
        if (t + 3 < NT) { stageA((t + 3) & 3); stageB((t + 3) & 3); }
        pA += BK; pB += BK;
        mfmaTile(FAa, FBa);
        schedInterleave();
        if (t < NT - 3) {
            asm volatile("s_waitcnt vmcnt(4)" ::: "memory");   // tile t+2 resident
        } else {
            asm volatile("s_waitcnt vmcnt(0)" ::: "memory");
        }
        asm volatile("s_barrier" ::: "memory");

        // ===== half 2: compute tile t+1 (set b); read tile t+2 -> set a =====
        if (t + 2 < NT) readFrags(FAa, FBa, (t + 2) & 3);
        if (t + 4 < NT) { stageA((t + 4) & 3); stageB((t + 4) & 3); }
        pA += BK; pB += BK;
        mfmaTile(FAb, FBb);
        schedInterleave();
        if (t + 1 < NT - 3) {
            asm volatile("s_waitcnt vmcnt(4)" ::: "memory");   // tile t+3 resident
        } else {
            asm volatile("s_waitcnt vmcnt(0)" ::: "memory");
        }
        asm volatile("s_barrier" ::: "memory");
    }

    // ---- epilogue: C/D layout col = lane&15, row = (lane>>4)*4 + reg
    const int rg = lane >> 4;
#pragma unroll
    for (int nf = 0; nf < 4; ++nf) {
        const int col = n0 + wc * 64 + nf * 16 + fr;
        const float bv = bias[col];
#pragma unroll
        for (int mf = 0; mf < 8; ++mf) {
            const int row = m0 + wr * 128 + mf * 16 + rg * 4;
            float* outp = C + (size_t)row * Ndim + col;
#pragma unroll
            for (int j = 0; j < 4; ++j) {
                float v = acc[mf][nf][j] + bv;
                v = fminf(fmaxf(v, -FMAXC), FMAXC);
                outp[(size_t)j * Ndim] = v;
            }
        }
    }
}

extern "C" void kernel_launch(void* const* d_in, const int* in_sizes, int n_in,
                              void* d_out, int out_size, void* d_ws, size_t ws_size,
                              hipStream_t stream) {
    const float* x    = (const float*)d_in[0];
    const int*   qw   = (const int*)d_in[1];
    const float* lut  = (const float*)d_in[2];
    const int*   rows = (const int*)d_in[3];
    const int*   cols = (const int*)d_in[4];
    const float* vals = (const float*)d_in[5];
    const float* bias = (const float*)d_in[6];
    float* out = (float*)d_out;

    ushort_t* x16 = (ushort_t*)d_ws;                       // 64 MiB
    ushort_t* w16 = x16 + (size_t)Mdim * Kdim;             // 32 MiB

    hipLaunchKernelGGL(dequant_kernel, dim3(Ndim), dim3(128), 0, stream,
                       qw, lut, rows, cols, vals, w16);
    hipLaunchKernelGGL(convx_kernel, dim3((Mdim * Kdim) / (256 * 8)), dim3(256), 0, stream,
                       x, x16);
    hipLaunchKernelGGL(gemm_kernel, dim3((Mdim / BM) * (Ndim / BN)), dim3(512), 0, stream,
                       x16, w16, bias, out);
}